// Round 1
// baseline (1377.630 us; speedup 1.0000x reference)
//
#include <hip/hip_runtime.h>
#include <math.h>

// MambaSlotAttention on MI355X.
// Key restructure: k/v feature projections are folded algebraically:
//   logits = sn @ (SCALE*Wq@Wk^T) @ fn^T      (never materialize k)
//   updates = ((attn^T @ fn) @ Wv) / mass     (never materialize v)
// fn = ln(features) computed once (bf16). All slot-space GEMMs via bf16 MFMA
// with f32 accumulation and fused epilogues.

typedef __attribute__((ext_vector_type(8))) short bf16x8;
typedef __attribute__((ext_vector_type(4))) float f32x4;

__device__ __forceinline__ float bf2f(ushort u){
  union { unsigned int i; float f; } c; c.i = ((unsigned int)u) << 16; return c.f;
}
__device__ __forceinline__ ushort f2bf(float x){
  union { float f; unsigned int i; } c; c.f = x;
  return (ushort)((c.i + 0x7fffu + ((c.i >> 16) & 1u)) >> 16);
}

// ---------------- LayerNorm over rows of 768 ----------------
template<bool OUTBF>
__global__ __launch_bounds__(256)
void ln_kernel(const float* __restrict__ x, const float* __restrict__ g,
               const float* __restrict__ bb, float* __restrict__ y,
               ushort* __restrict__ ybf)
{
  const long row = blockIdx.x;
  const float* xr = x + row*768;
  const int tid = threadIdx.x;
  const float v0 = xr[tid], v1 = xr[tid+256], v2 = xr[tid+512];
  float s = v0+v1+v2;
  float q = v0*v0 + v1*v1 + v2*v2;
  #pragma unroll
  for (int off=32; off>0; off>>=1){
    s += __shfl_down(s, off);
    q += __shfl_down(q, off);
  }
  __shared__ float red[8];
  __shared__ float mv[2];
  const int wave = tid>>6, lane = tid&63;
  if (lane==0){ red[wave]=s; red[4+wave]=q; }
  __syncthreads();
  if (tid==0){
    const float st = red[0]+red[1]+red[2]+red[3];
    const float qt = red[4]+red[5]+red[6]+red[7];
    const float mean = st*(1.f/768.f);
    const float var  = qt*(1.f/768.f) - mean*mean;
    mv[0]=mean; mv[1]=rsqrtf(var + 1e-5f);
  }
  __syncthreads();
  const float mean=mv[0], rstd=mv[1];
  #pragma unroll
  for (int i=0;i<3;i++){
    const int d = tid + (i<<8);
    const float v = (i==0)?v0:((i==1)?v1:v2);
    const float r = (v-mean)*rstd*g[d] + bb[d];
    if (OUTBF) ybf[row*768 + d] = f2bf(r);
    else       y[row*768 + d]   = r;
  }
}

// ---------------- weight convert / transpose to bf16 ----------------
struct CvtJobs {
  const float* src[16];
  ushort* dst[16];
  int R[16], Cc[16];
  int trans[16];
  int blk_off[17];
  int njobs;
};

__global__ __launch_bounds__(256)
void cvt_kernel(CvtJobs J)
{
  const int blk = blockIdx.x;
  int j = 0;
  while (j + 1 < J.njobs && blk >= J.blk_off[j+1]) ++j;
  const int lb = blk - J.blk_off[j];
  const float* src = J.src[j];
  ushort* dst = J.dst[j];
  const int tid = threadIdx.x;
  if (!J.trans[j]){
    const long base = (long)lb*1024 + tid*4;
    const float4 v = *(const float4*)(src + base);
    ushort4 o; o.x=f2bf(v.x); o.y=f2bf(v.y); o.z=f2bf(v.z); o.w=f2bf(v.w);
    *(ushort4*)(dst + base) = o;
  } else {
    const int C = J.Cc[j], R = J.R[j];
    const int tpr = C >> 5;
    const int tr = lb / tpr, tc = lb - tr*tpr;
    __shared__ float ts[32][33];
    const int r = tid>>3, c4 = (tid&7)<<2;
    const float4 v = *(const float4*)(src + (long)(tr*32 + r)*C + tc*32 + c4);
    ts[r][c4] = v.x; ts[r][c4+1] = v.y; ts[r][c4+2] = v.z; ts[r][c4+3] = v.w;
    __syncthreads();
    ushort4 o;
    o.x = f2bf(ts[c4  ][r]);
    o.y = f2bf(ts[c4+1][r]);
    o.z = f2bf(ts[c4+2][r]);
    o.w = f2bf(ts[c4+3][r]);
    *(ushort4*)(dst + (long)(tc*32 + r)*R + tr*32 + c4) = o;
  }
}

// ---------------- MFMA GEMM: C[M,N] = A[M,K](f32) @ BT[N,K](bf16)^T ----------------
enum { F_BIAS=1, F_GELU=2, F_RESID=4, F_ROWSCALE=8, F_OUTBF16=16, F_PAD16=32 };

template<int FLAGS>
__global__ __launch_bounds__(256,2)
void gemm_kernel(const float* __restrict__ A, const ushort* __restrict__ BT,
                 float* __restrict__ C, ushort* __restrict__ Cbf,
                 const int M, const int N, const int K, const int ntn,
                 const float* __restrict__ bias, const float* __restrict__ resid,
                 const float* __restrict__ mass, const float alpha)
{
  __shared__ ushort As[64][72];   // +8 pad: row stride 144B -> 2-way (free) frag reads
  __shared__ ushort Bs[64][72];
  const int tid  = threadIdx.x;
  const int bm   = blockIdx.x / ntn;
  const int bn   = blockIdx.x - bm*ntn;
  const int m0   = bm<<6, n0 = bn<<6;
  const int lane = tid & 63;
  const int wid  = tid >> 6;
  const int wr   = wid >> 1, wc = wid & 1;
  const int sr   = tid >> 2;
  const int scol = (tid & 3) << 4;
  const float*  Ap = A  + (long)(m0+sr)*K + scol;
  const ushort* Bp = BT + (long)(n0+sr)*K + scol;
  f32x4 acc00={0,0,0,0}, acc01={0,0,0,0}, acc10={0,0,0,0}, acc11={0,0,0,0};
  for (int k0=0; k0<K; k0+=64){
    const float4 a0 = *(const float4*)(Ap + k0);
    const float4 a1 = *(const float4*)(Ap + k0 + 4);
    const float4 a2 = *(const float4*)(Ap + k0 + 8);
    const float4 a3 = *(const float4*)(Ap + k0 + 12);
    const bf16x8 b0 = *(const bf16x8*)(Bp + k0);
    const bf16x8 b1 = *(const bf16x8*)(Bp + k0 + 8);
    bf16x8 w0, w1;
    w0[0]=(short)f2bf(a0.x); w0[1]=(short)f2bf(a0.y); w0[2]=(short)f2bf(a0.z); w0[3]=(short)f2bf(a0.w);
    w0[4]=(short)f2bf(a1.x); w0[5]=(short)f2bf(a1.y); w0[6]=(short)f2bf(a1.z); w0[7]=(short)f2bf(a1.w);
    w1[0]=(short)f2bf(a2.x); w1[1]=(short)f2bf(a2.y); w1[2]=(short)f2bf(a2.z); w1[3]=(short)f2bf(a2.w);
    w1[4]=(short)f2bf(a3.x); w1[5]=(short)f2bf(a3.y); w1[6]=(short)f2bf(a3.z); w1[7]=(short)f2bf(a3.w);
    *(bf16x8*)&As[sr][scol]   = w0;
    *(bf16x8*)&As[sr][scol+8] = w1;
    *(bf16x8*)&Bs[sr][scol]   = b0;
    *(bf16x8*)&Bs[sr][scol+8] = b1;
    __syncthreads();
    #pragma unroll
    for (int kk=0; kk<64; kk+=32){
      const int kr = kk + ((lane>>4)<<3);
      const bf16x8 aF0 = *(bf16x8*)&As[(wr<<5)      + (lane&15)][kr];
      const bf16x8 aF1 = *(bf16x8*)&As[(wr<<5) + 16 + (lane&15)][kr];
      const bf16x8 bF0 = *(bf16x8*)&Bs[(wc<<5)      + (lane&15)][kr];
      const bf16x8 bF1 = *(bf16x8*)&Bs[(wc<<5) + 16 + (lane&15)][kr];
      acc00 = __builtin_amdgcn_mfma_f32_16x16x32_bf16(aF0, bF0, acc00, 0,0,0);
      acc01 = __builtin_amdgcn_mfma_f32_16x16x32_bf16(aF0, bF1, acc01, 0,0,0);
      acc10 = __builtin_amdgcn_mfma_f32_16x16x32_bf16(aF1, bF0, acc10, 0,0,0);
      acc11 = __builtin_amdgcn_mfma_f32_16x16x32_bf16(aF1, bF1, acc11, 0,0,0);
    }
    __syncthreads();
  }
#define DO_EPI(ACCV, FM, FN) { \
    const int col = n0 + (wc<<5) + ((FN)<<4) + (lane&15); \
    const float bia = (FLAGS & F_BIAS) ? bias[col] : 0.f; \
    _Pragma("unroll") \
    for (int j=0;j<4;j++){ \
      const int row = m0 + (wr<<5) + ((FM)<<4) + ((lane>>4)<<2) + j; \
      float cvl = ACCV[j] * alpha; \
      if (FLAGS & F_ROWSCALE) cvl *= 1.f / fmaxf(mass[row], 1e-8f); \
      cvl += bia; \
      if (FLAGS & F_GELU) cvl = 0.5f*cvl*(1.f + erff(cvl*0.70710678118654752f)); \
      if (FLAGS & F_RESID) cvl += resid[(long)row*N + col]; \
      if (FLAGS & F_OUTBF16){ \
        const int orow = (FLAGS & F_PAD16) ? ((row/12)*16 + (row%12)) : row; \
        Cbf[(long)orow*N + col] = f2bf(cvl); \
      } else { \
        C[(long)row*N + col] = cvl; \
      } \
    } }
  DO_EPI(acc00,0,0)
  DO_EPI(acc01,0,1)
  DO_EPI(acc10,1,0)
  DO_EPI(acc11,1,1)
#undef DO_EPI
}

// ---------------- attention sweep pass 1: logits + softmax -> attn ----------------
// grid = B * 86 tiles of 16 n each. q2bf is [B][16][768] bf16 (rows 12..15 zero).
template<bool FINAL>
__global__ __launch_bounds__(256)
void attn_kernel(const ushort* __restrict__ q2bf, const ushort* __restrict__ fnb,
                 float* __restrict__ attnout, float* __restrict__ mass)
{
  __shared__ ushort q2s[16][776];
  __shared__ ushort fnt[16][776];
  __shared__ float lp[4][16][16];
  __shared__ float attns[16][16];
  const int NT = 86;
  const int b = blockIdx.x / NT, tile = blockIdx.x - b*NT;
  const int n0 = tile<<4;
  const int nn = min(16, 1369 - n0);
  const int tid = threadIdx.x;
  const int wave = tid>>6, lane = tid&63;
  {
    const int r = tid>>4, c0 = (tid&15)*48;
    const ushort* qsrc = q2bf + (long)b*12288 + r*768 + c0;
    #pragma unroll
    for (int i=0;i<6;i++)
      *(bf16x8*)&q2s[r][c0+8*i] = *(const bf16x8*)(qsrc + 8*i);
    if (n0 + r < 1369){
      const ushort* fsrc = fnb + ((long)b*1369 + n0 + r)*768 + c0;
      #pragma unroll
      for (int i=0;i<6;i++)
        *(bf16x8*)&fnt[r][c0+8*i] = *(const bf16x8*)(fsrc + 8*i);
    } else {
      const bf16x8 z = {0,0,0,0,0,0,0,0};
      #pragma unroll
      for (int i=0;i<6;i++)
        *(bf16x8*)&fnt[r][c0+8*i] = z;
    }
  }
  __syncthreads();
  {
    f32x4 acc = {0,0,0,0};
    #pragma unroll
    for (int dk=0; dk<192; dk+=32){
      const int d = wave*192 + dk + ((lane>>4)<<3);
      const bf16x8 a  = *(bf16x8*)&q2s[lane&15][d];
      const bf16x8 bb = *(bf16x8*)&fnt[lane&15][d];
      acc = __builtin_amdgcn_mfma_f32_16x16x32_bf16(a, bb, acc, 0,0,0);
    }
    #pragma unroll
    for (int j=0;j<4;j++)
      lp[wave][((lane>>4)<<2)+j][lane&15] = acc[j];
  }
  __syncthreads();
  if (tid < 16){
    const int n = tid;
    float lg[12];
    float mx = -1e30f;
    #pragma unroll
    for (int k=0;k<12;k++){
      const float sv = lp[0][k][n]+lp[1][k][n]+lp[2][k][n]+lp[3][k][n];
      lg[k]=sv; mx = fmaxf(mx, sv);
    }
    float ssum = 0.f;
    #pragma unroll
    for (int k=0;k<12;k++){ lg[k] = expf(lg[k]-mx); ssum += lg[k]; }
    const float inv = 1.f/ssum;
    #pragma unroll
    for (int k=0;k<12;k++) attns[n][k] = lg[k]*inv;
  }
  __syncthreads();
  if (tid < 192){
    const int n = tid/12, k = tid - (tid/12)*12;
    if (n < nn) attnout[((long)(b*1369 + n0 + n))*12 + k] = attns[n][k];
  }
  if (!FINAL){
    if (tid < 12){
      float sv = 0.f;
      for (int n=0;n<nn;n++) sv += attns[n][tid];
      atomicAdd(&mass[b*12 + tid], sv);
    }
  }
}

// ---------------- attention sweep pass 2: U[b,k,d] = sum_n attn[b,n,k]*fn[b,n,d] ----------------
// grid = B * 12 d-chunks of 64
__global__ __launch_bounds__(256)
void uacc_kernel(const float* __restrict__ attnb, const ushort* __restrict__ fnb,
                 float* __restrict__ U)
{
  __shared__ float red[4][12][64];
  const int b = blockIdx.x / 12, ch = blockIdx.x - (blockIdx.x/12)*12;
  const int d0 = ch<<6;
  const int tid = threadIdx.x, wave = tid>>6, lane = tid&63;
  const ushort* fb = fnb + (long)b*1369*768 + d0 + lane;
  const float* ab = attnb + (long)b*1369*12;
  float u[12] = {0,0,0,0,0,0,0,0,0,0,0,0};
  for (int n=wave; n<1369; n+=4){
    const float f = bf2f(fb[(long)n*768]);
    const float* an = ab + n*12;
    const float4 a0 = *(const float4*)(an);
    const float4 a1 = *(const float4*)(an+4);
    const float4 a2 = *(const float4*)(an+8);
    u[0]+=a0.x*f; u[1]+=a0.y*f; u[2]+=a0.z*f; u[3]+=a0.w*f;
    u[4]+=a1.x*f; u[5]+=a1.y*f; u[6]+=a1.z*f; u[7]+=a1.w*f;
    u[8]+=a2.x*f; u[9]+=a2.y*f; u[10]+=a2.z*f; u[11]+=a2.w*f;
  }
  #pragma unroll
  for (int k=0;k<12;k++) red[wave][k][lane] = u[k];
  __syncthreads();
  if (tid < 64){
    #pragma unroll
    for (int k=0;k<12;k++){
      const float sv = red[0][k][lane]+red[1][k][lane]+red[2][k][lane]+red[3][k][lane];
      U[((long)b*12+k)*768 + d0 + lane] = sv;
    }
  }
}

// ---------------- slot self-attention (seq len 12, head dim 96) ----------------
// grid = B*H
__global__ __launch_bounds__(256)
void slotattn_kernel(const float* __restrict__ qkv, float* __restrict__ o)
{
  __shared__ float qs[12][100], ks[12][100], vs[12][100];
  __shared__ float sc[12][16];
  const int b = blockIdx.x >> 3, h = blockIdx.x & 7;
  const int tid = threadIdx.x;
  for (int idx = tid; idx < 12*96; idx += 256){
    const int i = idx/96, d = idx - (idx/96)*96;
    const float* base = qkv + (long)(b*12+i)*2304 + h*96 + d;
    qs[i][d] = base[0];
    ks[i][d] = base[768];
    vs[i][d] = base[1536];
  }
  __syncthreads();
  if (tid < 144){
    const int i = tid/12, j = tid - (tid/12)*12;
    float s = 0.f;
    #pragma unroll 8
    for (int d=0; d<96; d++) s += qs[i][d]*ks[j][d];
    sc[i][j] = s * 0.10206207261596575f;   // 96^-0.5
  }
  __syncthreads();
  if (tid < 12){
    float mx = -1e30f;
    #pragma unroll
    for (int j=0;j<12;j++) mx = fmaxf(mx, sc[tid][j]);
    float e[12], ssum=0.f;
    #pragma unroll
    for (int j=0;j<12;j++){ e[j] = expf(sc[tid][j]-mx); ssum += e[j]; }
    const float inv = 1.f/ssum;
    #pragma unroll
    for (int j=0;j<12;j++) sc[tid][j] = e[j]*inv;
  }
  __syncthreads();
  for (int idx = tid; idx < 12*96; idx += 256){
    const int i = idx/96, d = idx - (idx/96)*96;
    float s = 0.f;
    #pragma unroll
    for (int j=0;j<12;j++) s += sc[i][j]*vs[j][d];
    o[(long)(b*12+i)*768 + h*96 + d] = s;
  }
}

// ---------------- host ----------------
extern "C" void kernel_launch(void* const* d_in, const int* in_sizes, int n_in,
                              void* d_out, int out_size, void* d_ws, size_t ws_size,
                              hipStream_t stream)
{
  (void)in_sizes; (void)n_in; (void)out_size; (void)ws_size;
  const float* features  = (const float*)d_in[0];
  const float* slots_init= (const float*)d_in[1];
  const float* nf_g = (const float*)d_in[2];
  const float* nf_b = (const float*)d_in[3];
  const float* ns_g = (const float*)d_in[4];
  const float* ns_b = (const float*)d_in[5];
  const float* Wq   = (const float*)d_in[6];
  const float* Wk   = (const float*)d_in[7];
  const float* Wv   = (const float*)d_in[8];
  const float* mg   = (const float*)d_in[9];
  const float* mbv  = (const float*)d_in[10];
  const float* mW1  = (const float*)d_in[11];
  const float* mb1  = (const float*)d_in[12];
  const float* mW2  = (const float*)d_in[13];
  const float* mb2  = (const float*)d_in[14];
  const float* b_ln1g = (const float*)d_in[15];
  const float* b_ln1b = (const float*)d_in[16];
  const float* b_Wqkv = (const float*)d_in[17];
  const float* b_bqkv = (const float*)d_in[18];
  const float* b_Wo   = (const float*)d_in[19];
  const float* b_bo   = (const float*)d_in[20];
  const float* b_ln2g = (const float*)d_in[21];
  const float* b_ln2b = (const float*)d_in[22];
  const float* b_W1   = (const float*)d_in[23];
  const float* b_b1   = (const float*)d_in[24];
  const float* b_W2   = (const float*)d_in[25];
  const float* b_b2   = (const float*)d_in[26];

  char* ws = (char*)d_ws;
  size_t off = 0;
  auto alloc = [&](size_t bytes)->char*{
    char* p = ws + off; off += (bytes + 255) & ~(size_t)255; return p;
  };
  ushort* fnb   = (ushort*)alloc(43808ull*768*2);
  ushort* Wq_bf = (ushort*)alloc(589824ull*2);
  ushort* WqkT  = (ushort*)alloc(589824ull*2);
  ushort* WvT   = (ushort*)alloc(589824ull*2);
  ushort* WqkvT = (ushort*)alloc(3ull*2304*768*2);
  ushort* WoT   = (ushort*)alloc(3ull*589824*2);
  ushort* W1T   = (ushort*)alloc(3ull*3072*768*2);
  ushort* W2T   = (ushort*)alloc(3ull*3072*768*2);
  ushort* mW1T  = (ushort*)alloc(3072ull*768*2);
  ushort* mW2T  = (ushort*)alloc(3072ull*768*2);
  float* slots = (float*)alloc(294912ull*4);
  float* sn    = (float*)alloc(294912ull*4);
  ushort* q2bf = (ushort*)alloc(32ull*16*768*2);
  float* massb = (float*)alloc(384ull*4);
  float* Ub    = (float*)alloc(294912ull*4);
  float* attnb = (float*)alloc(32ull*1369*12*4);
  float* h1    = (float*)alloc(294912ull*4);
  float* qkvb  = (float*)alloc(384ull*2304*4);
  float* ob    = (float*)alloc(294912ull*4);
  float* x1    = (float*)alloc(294912ull*4);
  float* h2    = (float*)alloc(294912ull*4);
  float* m1    = (float*)alloc(384ull*3072*4);
  float* sres  = (float*)alloc(294912ull*4);
  float* s_in  = (float*)alloc(294912ull*4);
  float* h3    = (float*)alloc(294912ull*4);
  float* m2    = (float*)alloc(384ull*3072*4);

  const float SCALEF = 0.03608439182435161f; // 768^-0.5

  hipMemcpyAsync(slots, slots_init, 294912ull*4, hipMemcpyDeviceToDevice, stream);
  hipMemsetAsync(q2bf, 0, 32ull*16*768*2, stream);

  // weight conversions (straight or transposed) to bf16, BT layout [N][K]
  CvtJobs J;
  int nj = 0, boff = 0;
  auto addjob = [&](const float* s, ushort* dptr, int R, int C, int tr){
    J.src[nj]=s; J.dst[nj]=dptr; J.R[nj]=R; J.Cc[nj]=C; J.trans[nj]=tr; J.blk_off[nj]=boff;
    boff += tr ? (R/32)*(C/32) : (R*C/1024); nj++;
  };
  addjob(Wq, Wq_bf, 768, 768, 0);                               // straight: BT for WqkT gemm
  addjob(Wv, WvT, 768, 768, 1);
  for (int t=0;t<3;t++) addjob(b_Wqkv + (size_t)t*768*2304, WqkvT + (size_t)t*2304*768, 768, 2304, 1);
  for (int t=0;t<3;t++) addjob(b_Wo   + (size_t)t*589824,   WoT   + (size_t)t*589824,   768, 768,  1);
  for (int t=0;t<3;t++) addjob(b_W1   + (size_t)t*768*3072, W1T   + (size_t)t*3072*768, 768, 3072, 1);
  for (int t=0;t<3;t++) addjob(b_W2   + (size_t)t*3072*768, W2T   + (size_t)t*768*3072, 3072, 768, 1);
  addjob(mW1, mW1T, 768, 3072, 1);
  addjob(mW2, mW2T, 3072, 768, 1);
  J.njobs = nj;
  J.blk_off[nj] = boff;
  cvt_kernel<<<dim3(boff), dim3(256), 0, stream>>>(J);

#define GEMM(FLG, Aptr, BTptr, Cptr, Cbfptr, Mm, Nn, Kk, biasp, residp, massp, alphav) \
  gemm_kernel<FLG><<<dim3(((Mm)>>6)*((Nn)>>6)), dim3(256), 0, stream>>>( \
      Aptr, BTptr, Cptr, Cbfptr, Mm, Nn, Kk, (Nn)>>6, biasp, residp, massp, alphav)

  // WqkT = SCALE * Wk @ Wq^T   (so q2 = sn @ Wqk with BT=WqkT)
  GEMM(F_OUTBF16, Wk, Wq_bf, (float*)nullptr, WqkT, 768, 768, 768,
       (const float*)nullptr, (const float*)nullptr, (const float*)nullptr, SCALEF);

  // fn = ln(features) -> bf16, once
  ln_kernel<true><<<dim3(43808), dim3(256), 0, stream>>>(features, nf_g, nf_b, nullptr, fnb);

  for (int t=0; t<3; t++){
    ln_kernel<false><<<dim3(384), dim3(256), 0, stream>>>(slots, ns_g, ns_b, sn, nullptr);
    GEMM(F_OUTBF16|F_PAD16, sn, WqkT, (float*)nullptr, q2bf, 384, 768, 768,
         (const float*)nullptr, (const float*)nullptr, (const float*)nullptr, 1.f);
    hipMemsetAsync(massb, 0, 384*4, stream);
    attn_kernel<false><<<dim3(32*86), dim3(256), 0, stream>>>(q2bf, fnb, attnb, massb);
    uacc_kernel<<<dim3(32*12), dim3(256), 0, stream>>>(attnb, fnb, Ub);
    // transformer block over slots (input x0 = sn)
    ln_kernel<false><<<dim3(384), dim3(256), 0, stream>>>(sn, b_ln1g + t*768, b_ln1b + t*768, h1, nullptr);
    GEMM(F_BIAS, h1, WqkvT + (size_t)t*2304*768, qkvb, (ushort*)nullptr, 384, 2304, 768,
         b_bqkv + t*2304, (const float*)nullptr, (const float*)nullptr, 1.f);
    slotattn_kernel<<<dim3(256), dim3(256), 0, stream>>>(qkvb, ob);
    GEMM(F_BIAS|F_RESID, ob, WoT + (size_t)t*589824, x1, (ushort*)nullptr, 384, 768, 768,
         b_bo + t*768, sn, (const float*)nullptr, 1.f);
    ln_kernel<false><<<dim3(384), dim3(256), 0, stream>>>(x1, b_ln2g + t*768, b_ln2b + t*768, h2, nullptr);
    GEMM(F_BIAS|F_GELU, h2, W1T + (size_t)t*3072*768, m1, (ushort*)nullptr, 384, 3072, 768,
         b_b1 + t*3072, (const float*)nullptr, (const float*)nullptr, 1.f);
    GEMM(F_BIAS|F_RESID, m1, W2T + (size_t)t*3072*768, sres, (ushort*)nullptr, 384, 768, 3072,
         b_b2 + t*768, x1, (const float*)nullptr, 1.f);
    // s_in = (U @ Wv)/mass + sres
    GEMM(F_ROWSCALE|F_RESID, Ub, WvT, s_in, (ushort*)nullptr, 384, 768, 768,
         (const float*)nullptr, sres, massb, 1.f);
    ln_kernel<false><<<dim3(384), dim3(256), 0, stream>>>(s_in, mg, mbv, h3, nullptr);
    GEMM(F_BIAS|F_GELU, h3, mW1T, m2, (ushort*)nullptr, 384, 3072, 768,
         mb1, (const float*)nullptr, (const float*)nullptr, 1.f);
    GEMM(F_BIAS|F_RESID, m2, mW2T, slots, (ushort*)nullptr, 384, 768, 3072,
         mb2, slots, (const float*)nullptr, 1.f);
  }

  // final masks with updated slots
  ln_kernel<false><<<dim3(384), dim3(256), 0, stream>>>(slots, ns_g, ns_b, sn, nullptr);
  GEMM(F_OUTBF16|F_PAD16, sn, WqkT, (float*)nullptr, q2bf, 384, 768, 768,
       (const float*)nullptr, (const float*)nullptr, (const float*)nullptr, 1.f);
  float* masks_out = (float*)d_out + 294912;
  attn_kernel<true><<<dim3(32*86), dim3(256), 0, stream>>>(q2bf, fnb, masks_out, nullptr);
  hipMemcpyAsync(d_out, slots, 294912ull*4, hipMemcpyDeviceToDevice, stream);
#undef GEMM
}

// Round 2
// 1143.016 us; speedup vs baseline: 1.2053x; 1.2053x over previous
//
#include <hip/hip_runtime.h>
#include <math.h>

// MambaSlotAttention on MI355X.
// logits = sn @ (SCALE*Wq@Wk^T) @ fn^T      (never materialize k)
// updates = ((attn^T @ fn) @ Wv) / mass     (never materialize v)
// fn = ln(features) computed once (bf16). Slot-space GEMMs via bf16 MFMA.

typedef __attribute__((ext_vector_type(8))) short bf16x8;
typedef __attribute__((ext_vector_type(4))) float f32x4;

__device__ __forceinline__ float bf2f(ushort u){
  union { unsigned int i; float f; } c; c.i = ((unsigned int)u) << 16; return c.f;
}
__device__ __forceinline__ ushort f2bf(float x){
  union { float f; unsigned int i; } c; c.f = x;
  return (ushort)((c.i + 0x7fffu + ((c.i >> 16) & 1u)) >> 16);
}

// ---------------- LayerNorm over rows of 768 ----------------
template<bool OUTBF>
__global__ __launch_bounds__(256)
void ln_kernel(const float* __restrict__ x, const float* __restrict__ g,
               const float* __restrict__ bb, float* __restrict__ y,
               ushort* __restrict__ ybf)
{
  const long row = blockIdx.x;
  const float* xr = x + row*768;
  const int tid = threadIdx.x;
  const float v0 = xr[tid], v1 = xr[tid+256], v2 = xr[tid+512];
  float s = v0+v1+v2;
  float q = v0*v0 + v1*v1 + v2*v2;
  #pragma unroll
  for (int off=32; off>0; off>>=1){
    s += __shfl_down(s, off);
    q += __shfl_down(q, off);
  }
  __shared__ float red[8];
  __shared__ float mv[2];
  const int wave = tid>>6, lane = tid&63;
  if (lane==0){ red[wave]=s; red[4+wave]=q; }
  __syncthreads();
  if (tid==0){
    const float st = red[0]+red[1]+red[2]+red[3];
    const float qt = red[4]+red[5]+red[6]+red[7];
    const float mean = st*(1.f/768.f);
    const float var  = qt*(1.f/768.f) - mean*mean;
    mv[0]=mean; mv[1]=rsqrtf(var + 1e-5f);
  }
  __syncthreads();
  const float mean=mv[0], rstd=mv[1];
  #pragma unroll
  for (int i=0;i<3;i++){
    const int d = tid + (i<<8);
    const float v = (i==0)?v0:((i==1)?v1:v2);
    const float r = (v-mean)*rstd*g[d] + bb[d];
    if (OUTBF) ybf[row*768 + d] = f2bf(r);
    else       y[row*768 + d]   = r;
  }
}

// ---------------- weight convert / transpose to bf16 ----------------
struct CvtJobs {
  const float* src[16];
  ushort* dst[16];
  int R[16], Cc[16];
  int trans[16];
  int blk_off[17];
  int njobs;
};

__global__ __launch_bounds__(256)
void cvt_kernel(CvtJobs J)
{
  const int blk = blockIdx.x;
  int j = 0;
  while (j + 1 < J.njobs && blk >= J.blk_off[j+1]) ++j;
  const int lb = blk - J.blk_off[j];
  const float* src = J.src[j];
  ushort* dst = J.dst[j];
  const int tid = threadIdx.x;
  if (!J.trans[j]){
    const long base = (long)lb*1024 + tid*4;
    const float4 v = *(const float4*)(src + base);
    ushort4 o; o.x=f2bf(v.x); o.y=f2bf(v.y); o.z=f2bf(v.z); o.w=f2bf(v.w);
    *(ushort4*)(dst + base) = o;
  } else {
    const int C = J.Cc[j], R = J.R[j];
    const int tpr = C >> 5;
    const int tr = lb / tpr, tc = lb - tr*tpr;
    __shared__ float ts[32][33];
    const int r = tid>>3, c4 = (tid&7)<<2;
    const float4 v = *(const float4*)(src + (long)(tr*32 + r)*C + tc*32 + c4);
    ts[r][c4] = v.x; ts[r][c4+1] = v.y; ts[r][c4+2] = v.z; ts[r][c4+3] = v.w;
    __syncthreads();
    ushort4 o;
    o.x = f2bf(ts[c4  ][r]);
    o.y = f2bf(ts[c4+1][r]);
    o.z = f2bf(ts[c4+2][r]);
    o.w = f2bf(ts[c4+3][r]);
    *(ushort4*)(dst + (long)(tc*32 + r)*R + tr*32 + c4) = o;
  }
}

// ---------------- MFMA GEMM: C[M,N] = A[M,K](f32) @ BT[N,K](bf16)^T ----------------
enum { F_BIAS=1, F_GELU=2, F_RESID=4, F_ROWSCALE=8, F_OUTBF16=16, F_PAD16=32 };

template<int FLAGS>
__global__ __launch_bounds__(256,2)
void gemm_kernel(const float* __restrict__ A, const ushort* __restrict__ BT,
                 float* __restrict__ C, ushort* __restrict__ Cbf,
                 const int M, const int N, const int K, const int ntn,
                 const float* __restrict__ bias, const float* __restrict__ resid,
                 const float* __restrict__ mass, const float alpha)
{
  __shared__ ushort As[64][72];
  __shared__ ushort Bs[64][72];
  const int tid  = threadIdx.x;
  const int bm   = blockIdx.x / ntn;
  const int bn   = blockIdx.x - bm*ntn;
  const int m0   = bm<<6, n0 = bn<<6;
  const int lane = tid & 63;
  const int wid  = tid >> 6;
  const int wr   = wid >> 1, wc = wid & 1;
  const int sr   = tid >> 2;
  const int scol = (tid & 3) << 4;
  const float*  Ap = A  + (long)(m0+sr)*K + scol;
  const ushort* Bp = BT + (long)(n0+sr)*K + scol;
  f32x4 acc00={0,0,0,0}, acc01={0,0,0,0}, acc10={0,0,0,0}, acc11={0,0,0,0};
  for (int k0=0; k0<K; k0+=64){
    const float4 a0 = *(const float4*)(Ap + k0);
    const float4 a1 = *(const float4*)(Ap + k0 + 4);
    const float4 a2 = *(const float4*)(Ap + k0 + 8);
    const float4 a3 = *(const float4*)(Ap + k0 + 12);
    const bf16x8 b0 = *(const bf16x8*)(Bp + k0);
    const bf16x8 b1 = *(const bf16x8*)(Bp + k0 + 8);
    bf16x8 w0, w1;
    w0[0]=(short)f2bf(a0.x); w0[1]=(short)f2bf(a0.y); w0[2]=(short)f2bf(a0.z); w0[3]=(short)f2bf(a0.w);
    w0[4]=(short)f2bf(a1.x); w0[5]=(short)f2bf(a1.y); w0[6]=(short)f2bf(a1.z); w0[7]=(short)f2bf(a1.w);
    w1[0]=(short)f2bf(a2.x); w1[1]=(short)f2bf(a2.y); w1[2]=(short)f2bf(a2.z); w1[3]=(short)f2bf(a2.w);
    w1[4]=(short)f2bf(a3.x); w1[5]=(short)f2bf(a3.y); w1[6]=(short)f2bf(a3.z); w1[7]=(short)f2bf(a3.w);
    *(bf16x8*)&As[sr][scol]   = w0;
    *(bf16x8*)&As[sr][scol+8] = w1;
    *(bf16x8*)&Bs[sr][scol]   = b0;
    *(bf16x8*)&Bs[sr][scol+8] = b1;
    __syncthreads();
    #pragma unroll
    for (int kk=0; kk<64; kk+=32){
      const int kr = kk + ((lane>>4)<<3);
      const bf16x8 aF0 = *(bf16x8*)&As[(wr<<5)      + (lane&15)][kr];
      const bf16x8 aF1 = *(bf16x8*)&As[(wr<<5) + 16 + (lane&15)][kr];
      const bf16x8 bF0 = *(bf16x8*)&Bs[(wc<<5)      + (lane&15)][kr];
      const bf16x8 bF1 = *(bf16x8*)&Bs[(wc<<5) + 16 + (lane&15)][kr];
      acc00 = __builtin_amdgcn_mfma_f32_16x16x32_bf16(aF0, bF0, acc00, 0,0,0);
      acc01 = __builtin_amdgcn_mfma_f32_16x16x32_bf16(aF0, bF1, acc01, 0,0,0);
      acc10 = __builtin_amdgcn_mfma_f32_16x16x32_bf16(aF1, bF0, acc10, 0,0,0);
      acc11 = __builtin_amdgcn_mfma_f32_16x16x32_bf16(aF1, bF1, acc11, 0,0,0);
    }
    __syncthreads();
  }
#define DO_EPI(ACCV, FM, FN) { \
    const int col = n0 + (wc<<5) + ((FN)<<4) + (lane&15); \
    const float bia = (FLAGS & F_BIAS) ? bias[col] : 0.f; \
    _Pragma("unroll") \
    for (int j=0;j<4;j++){ \
      const int row = m0 + (wr<<5) + ((FM)<<4) + ((lane>>4)<<2) + j; \
      float cvl = ACCV[j] * alpha; \
      if (FLAGS & F_ROWSCALE) cvl *= 1.f / fmaxf(mass[row], 1e-8f); \
      cvl += bia; \
      if (FLAGS & F_GELU) cvl = 0.5f*cvl*(1.f + erff(cvl*0.70710678118654752f)); \
      if (FLAGS & F_RESID) cvl += resid[(long)row*N + col]; \
      if (FLAGS & F_OUTBF16){ \
        const int orow = (FLAGS & F_PAD16) ? ((row/12)*16 + (row%12)) : row; \
        Cbf[(long)orow*N + col] = f2bf(cvl); \
      } else { \
        C[(long)row*N + col] = cvl; \
      } \
    } }
  DO_EPI(acc00,0,0)
  DO_EPI(acc01,0,1)
  DO_EPI(acc10,1,0)
  DO_EPI(acc11,1,1)
#undef DO_EPI
}

// ---------------- attention pass 1: logits + softmax -> attn ----------------
// grid = B * 86 tiles of 16 n. q2bf is [B][16][768] bf16 (rows 12..15 unused).
// No LDS staging: every q2/fn element is consumed exactly once per block.
// fnb must have >=15 valid-readable rows past the end (zero-padded).
template<bool FINAL>
__global__ __launch_bounds__(256)
void attn_kernel(const ushort* __restrict__ q2bf, const ushort* __restrict__ fnb,
                 float* __restrict__ attnout, float* __restrict__ mass)
{
  __shared__ float lp[4][16][16];
  __shared__ float attns[16][16];
  const int NT = 86;
  const int b = blockIdx.x / NT, tile = blockIdx.x - b*NT;
  const int n0 = tile<<4;
  const int nn = min(16, 1369 - n0);
  const int tid = threadIdx.x;
  const int wave = tid>>6, lane = tid&63;
  const ushort* qbase = q2bf + (long)b*12288 + (long)(lane&15)*768 + ((lane>>4)<<3) + wave*192;
  const ushort* fbase = fnb + ((long)b*1369 + n0 + (lane&15))*768 + ((lane>>4)<<3) + wave*192;
  {
    f32x4 acc = {0,0,0,0};
    #pragma unroll
    for (int dk=0; dk<192; dk+=32){
      const bf16x8 a  = *(const bf16x8*)(qbase + dk);
      const bf16x8 bb = *(const bf16x8*)(fbase + dk);
      acc = __builtin_amdgcn_mfma_f32_16x16x32_bf16(a, bb, acc, 0,0,0);
    }
    #pragma unroll
    for (int j=0;j<4;j++)
      lp[wave][((lane>>4)<<2)+j][lane&15] = acc[j];
  }
  __syncthreads();
  if (tid < 16){
    const int n = tid;
    float lg[12];
    float mx = -1e30f;
    #pragma unroll
    for (int k=0;k<12;k++){
      const float sv = lp[0][k][n]+lp[1][k][n]+lp[2][k][n]+lp[3][k][n];
      lg[k]=sv; mx = fmaxf(mx, sv);
    }
    float ssum = 0.f;
    #pragma unroll
    for (int k=0;k<12;k++){ lg[k] = expf(lg[k]-mx); ssum += lg[k]; }
    const float inv = 1.f/ssum;
    #pragma unroll
    for (int k=0;k<12;k++) attns[n][k] = lg[k]*inv;
  }
  __syncthreads();
  if (tid < 192){
    const int n = tid/12, k = tid - (tid/12)*12;
    if (n < nn) attnout[((long)(b*1369 + n0 + n))*12 + k] = attns[n][k];
  }
  if (!FINAL){
    if (tid < 12){
      float sv = 0.f;
      for (int n=0;n<nn;n++) sv += attns[n][tid];
      atomicAdd(&mass[b*12 + tid], sv);
    }
  }
}

// ---------------- attention pass 2: Up[b,ch,k,d] = sum_{n in chunk} attn[b,n,k]*fn[b,n,d] ----------------
// grid = B*16 chunks of 86 rows, block 384: thread owns d-pair (d0 = tid*2),
// so each row load is one fully-coalesced 1536B block-wide sweep (4B/lane).
__global__ __launch_bounds__(384)
void uacc2_kernel(const float* __restrict__ attnb, const ushort* __restrict__ fnb,
                  float* __restrict__ Up)
{
  __shared__ float as_attn[86*12];
  const int b = blockIdx.x >> 4, ch = blockIdx.x & 15;
  const int tid = threadIdx.x;
  const int nbase = ch*86;
  const int nrows = min(86, 1369 - nbase);
  const float* ab = attnb + ((long)b*1369 + nbase)*12;
  for (int i = tid; i < nrows*12; i += 384) as_attn[i] = ab[i];
  __syncthreads();
  const int d0 = tid*2;
  const ushort* fb = fnb + ((long)b*1369 + nbase)*768 + d0;
  float u0[12] = {0,0,0,0,0,0,0,0,0,0,0,0};
  float u1[12] = {0,0,0,0,0,0,0,0,0,0,0,0};
  #pragma unroll 2
  for (int n=0; n<nrows; n++){
    const uint fv = *(const uint*)(fb + (long)n*768);
    const float f0 = bf2f((ushort)fv);
    const float f1 = bf2f((ushort)(fv>>16));
    const float* an = &as_attn[n*12];
    const float4 a0 = *(const float4*)(an);
    const float4 a1 = *(const float4*)(an+4);
    const float4 a2 = *(const float4*)(an+8);
    u0[0]+=a0.x*f0; u0[1]+=a0.y*f0; u0[2]+=a0.z*f0; u0[3]+=a0.w*f0;
    u0[4]+=a1.x*f0; u0[5]+=a1.y*f0; u0[6]+=a1.z*f0; u0[7]+=a1.w*f0;
    u0[8]+=a2.x*f0; u0[9]+=a2.y*f0; u0[10]+=a2.z*f0; u0[11]+=a2.w*f0;
    u1[0]+=a0.x*f1; u1[1]+=a0.y*f1; u1[2]+=a0.z*f1; u1[3]+=a0.w*f1;
    u1[4]+=a1.x*f1; u1[5]+=a1.y*f1; u1[6]+=a1.z*f1; u1[7]+=a1.w*f1;
    u1[8]+=a2.x*f1; u1[9]+=a2.y*f1; u1[10]+=a2.z*f1; u1[11]+=a2.w*f1;
  }
  float* ub = Up + ((long)(b*16 + ch)*12)*768 + d0;
  #pragma unroll
  for (int k=0;k<12;k++){
    float2 w; w.x = u0[k]; w.y = u1[k];
    *(float2*)(ub + (long)k*768) = w;
  }
}

// reduce 16 chunk-partials -> U[b,k,d]
__global__ __launch_bounds__(256)
void ureduce_kernel(const float* __restrict__ Up, float* __restrict__ U)
{
  const long o = (long)blockIdx.x*256 + threadIdx.x;   // < 32*12*768
  const int b = (int)(o / 9216);
  const int r = (int)(o - (long)b*9216);
  float s = 0.f;
  #pragma unroll
  for (int c=0;c<16;c++) s += Up[((long)(b*16 + c))*9216 + r];
  U[o] = s;
}

// ---------------- slot self-attention (seq len 12, head dim 96) ----------------
__global__ __launch_bounds__(256)
void slotattn_kernel(const float* __restrict__ qkv, float* __restrict__ o)
{
  __shared__ float qs[12][100], ks[12][100], vs[12][100];
  __shared__ float sc[12][16];
  const int b = blockIdx.x >> 3, h = blockIdx.x & 7;
  const int tid = threadIdx.x;
  for (int idx = tid; idx < 12*96; idx += 256){
    const int i = idx/96, d = idx - (idx/96)*96;
    const float* base = qkv + (long)(b*12+i)*2304 + h*96 + d;
    qs[i][d] = base[0];
    ks[i][d] = base[768];
    vs[i][d] = base[1536];
  }
  __syncthreads();
  if (tid < 144){
    const int i = tid/12, j = tid - (tid/12)*12;
    float s = 0.f;
    #pragma unroll 8
    for (int d=0; d<96; d++) s += qs[i][d]*ks[j][d];
    sc[i][j] = s * 0.10206207261596575f;
  }
  __syncthreads();
  if (tid < 12){
    float mx = -1e30f;
    #pragma unroll
    for (int j=0;j<12;j++) mx = fmaxf(mx, sc[tid][j]);
    float e[12], ssum=0.f;
    #pragma unroll
    for (int j=0;j<12;j++){ e[j] = expf(sc[tid][j]-mx); ssum += e[j]; }
    const float inv = 1.f/ssum;
    #pragma unroll
    for (int j=0;j<12;j++) sc[tid][j] = e[j]*inv;
  }
  __syncthreads();
  for (int idx = tid; idx < 12*96; idx += 256){
    const int i = idx/96, d = idx - (idx/96)*96;
    float s = 0.f;
    #pragma unroll
    for (int j=0;j<12;j++) s += sc[i][j]*vs[j][d];
    o[(long)(b*12+i)*768 + h*96 + d] = s;
  }
}

// ---------------- host ----------------
extern "C" void kernel_launch(void* const* d_in, const int* in_sizes, int n_in,
                              void* d_out, int out_size, void* d_ws, size_t ws_size,
                              hipStream_t stream)
{
  (void)in_sizes; (void)n_in; (void)out_size; (void)ws_size;
  const float* features  = (const float*)d_in[0];
  const float* slots_init= (const float*)d_in[1];
  const float* nf_g = (const float*)d_in[2];
  const float* nf_b = (const float*)d_in[3];
  const float* ns_g = (const float*)d_in[4];
  const float* ns_b = (const float*)d_in[5];
  const float* Wq   = (const float*)d_in[6];
  const float* Wk   = (const float*)d_in[7];
  const float* Wv   = (const float*)d_in[8];
  const float* mg   = (const float*)d_in[9];
  const float* mbv  = (const float*)d_in[10];
  const float* mW1  = (const float*)d_in[11];
  const float* mb1  = (const float*)d_in[12];
  const float* mW2  = (const float*)d_in[13];
  const float* mb2  = (const float*)d_in[14];
  const float* b_ln1g = (const float*)d_in[15];
  const float* b_ln1b = (const float*)d_in[16];
  const float* b_Wqkv = (const float*)d_in[17];
  const float* b_bqkv = (const float*)d_in[18];
  const float* b_Wo   = (const float*)d_in[19];
  const float* b_bo   = (const float*)d_in[20];
  const float* b_ln2g = (const float*)d_in[21];
  const float* b_ln2b = (const float*)d_in[22];
  const float* b_W1   = (const float*)d_in[23];
  const float* b_b1   = (const float*)d_in[24];
  const float* b_W2   = (const float*)d_in[25];
  const float* b_b2   = (const float*)d_in[26];

  char* ws = (char*)d_ws;
  size_t off = 0;
  auto alloc = [&](size_t bytes)->char*{
    char* p = ws + off; off += (bytes + 255) & ~(size_t)255; return p;
  };
  ushort* fnb   = (ushort*)alloc((43808ull+16)*768*2);   // +16 zero pad rows
  ushort* Wq_bf = (ushort*)alloc(589824ull*2);
  ushort* WqkT  = (ushort*)alloc(589824ull*2);
  ushort* WvT   = (ushort*)alloc(589824ull*2);
  ushort* WqkvT = (ushort*)alloc(3ull*2304*768*2);
  ushort* WoT   = (ushort*)alloc(3ull*589824*2);
  ushort* W1T   = (ushort*)alloc(3ull*3072*768*2);
  ushort* W2T   = (ushort*)alloc(3ull*3072*768*2);
  ushort* mW1T  = (ushort*)alloc(3072ull*768*2);
  ushort* mW2T  = (ushort*)alloc(3072ull*768*2);
  float* slots = (float*)alloc(294912ull*4);
  float* sn    = (float*)alloc(294912ull*4);
  ushort* q2bf = (ushort*)alloc(32ull*16*768*2);
  float* massb = (float*)alloc(384ull*4);
  float* Ub    = (float*)alloc(294912ull*4);
  float* Upart = (float*)alloc(32ull*16*12*768*4);
  float* attnb = (float*)alloc(32ull*1369*12*4);
  float* h1    = (float*)alloc(294912ull*4);
  float* qkvb  = (float*)alloc(384ull*2304*4);
  float* ob    = (float*)alloc(294912ull*4);
  float* x1    = (float*)alloc(294912ull*4);
  float* h2    = (float*)alloc(294912ull*4);
  float* m1    = (float*)alloc(384ull*3072*4);
  float* sres  = (float*)alloc(294912ull*4);
  float* s_in  = (float*)alloc(294912ull*4);
  float* h3    = (float*)alloc(294912ull*4);
  float* m2    = (float*)alloc(384ull*3072*4);

  const float SCALEF = 0.03608439182435161f; // 768^-0.5

  hipMemcpyAsync(slots, slots_init, 294912ull*4, hipMemcpyDeviceToDevice, stream);
  hipMemsetAsync(q2bf, 0, 32ull*16*768*2, stream);
  hipMemsetAsync(fnb + 43808ull*768, 0, 16ull*768*2, stream);  // zero pad rows (ws re-poisoned each call)

  CvtJobs J;
  int nj = 0, boff = 0;
  auto addjob = [&](const float* s, ushort* dptr, int R, int C, int tr){
    J.src[nj]=s; J.dst[nj]=dptr; J.R[nj]=R; J.Cc[nj]=C; J.trans[nj]=tr; J.blk_off[nj]=boff;
    boff += tr ? (R/32)*(C/32) : (R*C/1024); nj++;
  };
  addjob(Wq, Wq_bf, 768, 768, 0);
  addjob(Wv, WvT, 768, 768, 1);
  for (int t=0;t<3;t++) addjob(b_Wqkv + (size_t)t*768*2304, WqkvT + (size_t)t*2304*768, 768, 2304, 1);
  for (int t=0;t<3;t++) addjob(b_Wo   + (size_t)t*589824,   WoT   + (size_t)t*589824,   768, 768,  1);
  for (int t=0;t<3;t++) addjob(b_W1   + (size_t)t*768*3072, W1T   + (size_t)t*3072*768, 768, 3072, 1);
  for (int t=0;t<3;t++) addjob(b_W2   + (size_t)t*3072*768, W2T   + (size_t)t*768*3072, 3072, 768, 1);
  addjob(mW1, mW1T, 768, 3072, 1);
  addjob(mW2, mW2T, 3072, 768, 1);
  J.njobs = nj;
  J.blk_off[nj] = boff;
  cvt_kernel<<<dim3(boff), dim3(256), 0, stream>>>(J);

#define GEMM(FLG, Aptr, BTptr, Cptr, Cbfptr, Mm, Nn, Kk, biasp, residp, massp, alphav) \
  gemm_kernel<FLG><<<dim3(((Mm)>>6)*((Nn)>>6)), dim3(256), 0, stream>>>( \
      Aptr, BTptr, Cptr, Cbfptr, Mm, Nn, Kk, (Nn)>>6, biasp, residp, massp, alphav)

  GEMM(F_OUTBF16, Wk, Wq_bf, (float*)nullptr, WqkT, 768, 768, 768,
       (const float*)nullptr, (const float*)nullptr, (const float*)nullptr, SCALEF);

  ln_kernel<true><<<dim3(43808), dim3(256), 0, stream>>>(features, nf_g, nf_b, nullptr, fnb);

  for (int t=0; t<3; t++){
    ln_kernel<false><<<dim3(384), dim3(256), 0, stream>>>(slots, ns_g, ns_b, sn, nullptr);
    GEMM(F_OUTBF16|F_PAD16, sn, WqkT, (float*)nullptr, q2bf, 384, 768, 768,
         (const float*)nullptr, (const float*)nullptr, (const float*)nullptr, 1.f);
    hipMemsetAsync(massb, 0, 384*4, stream);
    attn_kernel<false><<<dim3(32*86), dim3(256), 0, stream>>>(q2bf, fnb, attnb, massb);
    uacc2_kernel<<<dim3(32*16), dim3(384), 0, stream>>>(attnb, fnb, Upart);
    ureduce_kernel<<<dim3(1152), dim3(256), 0, stream>>>(Upart, Ub);
    ln_kernel<false><<<dim3(384), dim3(256), 0, stream>>>(sn, b_ln1g + t*768, b_ln1b + t*768, h1, nullptr);
    GEMM(F_BIAS, h1, WqkvT + (size_t)t*2304*768, qkvb, (ushort*)nullptr, 384, 2304, 768,
         b_bqkv + t*2304, (const float*)nullptr, (const float*)nullptr, 1.f);
    slotattn_kernel<<<dim3(256), dim3(256), 0, stream>>>(qkvb, ob);
    GEMM(F_BIAS|F_RESID, ob, WoT + (size_t)t*589824, x1, (ushort*)nullptr, 384, 768, 768,
         b_bo + t*768, sn, (const float*)nullptr, 1.f);
    ln_kernel<false><<<dim3(384), dim3(256), 0, stream>>>(x1, b_ln2g + t*768, b_ln2b + t*768, h2, nullptr);
    GEMM(F_BIAS|F_GELU, h2, W1T + (size_t)t*3072*768, m1, (ushort*)nullptr, 384, 3072, 768,
         b_b1 + t*3072, (const float*)nullptr, (const float*)nullptr, 1.f);
    GEMM(F_BIAS|F_RESID, m1, W2T + (size_t)t*3072*768, sres, (ushort*)nullptr, 384, 768, 3072,
         b_b2 + t*768, x1, (const float*)nullptr, 1.f);
    GEMM(F_ROWSCALE|F_RESID, Ub, WvT, s_in, (ushort*)nullptr, 384, 768, 768,
         (const float*)nullptr, sres, massb, 1.f);
    ln_kernel<false><<<dim3(384), dim3(256), 0, stream>>>(s_in, mg, mbv, h3, nullptr);
    GEMM(F_BIAS|F_GELU, h3, mW1T, m2, (ushort*)nullptr, 384, 3072, 768,
         mb1, (const float*)nullptr, (const float*)nullptr, 1.f);
    GEMM(F_BIAS|F_RESID, m2, mW2T, slots, (ushort*)nullptr, 384, 768, 3072,
         mb2, slots, (const float*)nullptr, 1.f);
  }

  ln_kernel<false><<<dim3(384), dim3(256), 0, stream>>>(slots, ns_g, ns_b, sn, nullptr);
  GEMM(F_OUTBF16|F_PAD16, sn, WqkT, (float*)nullptr, q2bf, 384, 768, 768,
       (const float*)nullptr, (const float*)nullptr, (const float*)nullptr, 1.f);
  float* masks_out = (float*)d_out + 294912;
  attn_kernel<true><<<dim3(32*86), dim3(256), 0, stream>>>(q2bf, fnb, masks_out, nullptr);
  hipMemcpyAsync(d_out, slots, 294912ull*4, hipMemcpyDeviceToDevice, stream);
#undef GEMM
}